// Round 38
// baseline (247.395 us; speedup 1.0000x reference)
//
#include <hip/hip_runtime.h>
#include <hip/hip_fp16.h>

#define NN 100000      // nodes
#define NE 1200000     // edges
#define FIN 22
#define HD 64
#define NC 6
#define BN_EPS 1e-5f
#define EPB 4096                          // edges per phase-1 block
#define MB1 ((NE + EPB - 1) / EPB)        // 293
#define NBK 196                           // coarse buckets of 512 nodes (dst>>9)
#define ENPB 16                           // nodes per embed block
#define EMB_NB (NN / ENPB)                // 6250 (exact)
#define GAT_NB ((NN + 3) / 4)             // 25000 (exact: 4*GAT_NB == NN)
#define GEMM_NB ((NN + 63) / 64)          // 1563

// ---------------- fused: coarse-bucket histogram (LDS) || embed (16 nodes/blk) ----------------
__global__ void k_hist_embed(const int* __restrict__ dst, int* __restrict__ bktCnt,
                             const float* __restrict__ x, const float* __restrict__ W,
                             const float* __restrict__ b, float* __restrict__ h) {
    __shared__ float Ws[FIN * HD];
    __shared__ float xs[ENPB][FIN];
    __shared__ int hist[256];
    int t = threadIdx.x;
    if (blockIdx.x < MB1) {
        hist[t] = 0;
        __syncthreads();
        int e0 = blockIdx.x * EPB;
        int e1 = min(e0 + EPB, NE);
        for (int e = e0 + t; e < e1; e += 256)
            atomicAdd(&hist[dst[e] >> 9], 1);          // LDS atomic
        __syncthreads();
        if (t < NBK && hist[t] > 0) atomicAdd(&bktCnt[t], hist[t]);  // <=196/block global
        return;
    }
    int bid = blockIdx.x - MB1;
    int n0 = bid * ENPB;
    for (int i = t; i < FIN * HD; i += 256) Ws[i] = W[i];
    for (int i = t; i < ENPB * FIN; i += 256)
        xs[i / FIN][i % FIN] = x[(long)(n0 + i / FIN) * FIN + i % FIN];
    __syncthreads();
    int f = t & 63;
    int lq = t >> 6;                     // wave id 0..3 -> base node
    float bf = b[f];
    float a0 = bf, a1 = bf, a2 = bf, a3 = bf;
#pragma unroll
    for (int k = 0; k < FIN; ++k) {
        float wk = Ws[k * HD + f];
        a0 = fmaf(xs[lq][k],      wk, a0);
        a1 = fmaf(xs[lq + 4][k],  wk, a1);
        a2 = fmaf(xs[lq + 8][k],  wk, a2);
        a3 = fmaf(xs[lq + 12][k], wk, a3);
    }
    h[(long)(n0 + lq) * HD + f]      = fmaxf(a0, 0.f);
    h[(long)(n0 + lq + 4) * HD + f]  = fmaxf(a1, 0.f);
    h[(long)(n0 + lq + 8) * HD + f]  = fmaxf(a2, 0.f);
    h[(long)(n0 + lq + 12) * HD + f] = fmaxf(a3, 0.f);
}

// ---------------- bucket scan (1 block): bktBase = excl scan; cursor init ----------------
__global__ void k_bkt_scan(const int* __restrict__ bktCnt, int* __restrict__ bktBase,
                           int* __restrict__ cursor) {
    __shared__ int s[256];
    int t = threadIdx.x;
    int v = (t < NBK) ? bktCnt[t] : 0;
    s[t] = v;
    __syncthreads();
    for (int off = 1; off < 256; off <<= 1) {
        int x = (t >= off) ? s[t - off] : 0;
        __syncthreads();
        s[t] += x;
        __syncthreads();
    }
    int excl = s[t] - v;
    if (t < NBK) { bktBase[t] = excl; cursor[t] = excl; }
    if (t == NBK - 1) bktBase[NBK] = excl + v;          // = NE
}

// ---------------- bin scatter: edges -> bucket-contiguous (src,dst) pairs ----------------
__global__ void k_bin(const int* __restrict__ src, const int* __restrict__ dst,
                      int* __restrict__ cursor, int2* __restrict__ binned) {
    __shared__ int hist[256];
    __shared__ int sbase[256];
    __shared__ int lcur[256];
    int t = threadIdx.x;
    hist[t] = 0;
    __syncthreads();
    int e0 = blockIdx.x * EPB;
    int e1 = min(e0 + EPB, NE);
    for (int e = e0 + t; e < e1; e += 256)
        atomicAdd(&hist[dst[e] >> 9], 1);
    __syncthreads();
    if (hist[t] > 0) sbase[t] = atomicAdd(&cursor[t], hist[t]);  // claim range
    lcur[t] = 0;
    __syncthreads();
    for (int e = e0 + t; e < e1; e += 256) {
        int d = dst[e];
        int bk = d >> 9;
        int idx = atomicAdd(&lcur[bk], 1);              // LDS atomic
        binned[sbase[bk] + idx] = make_int2(src[e], d);
    }
}

// ---------------- per-bucket row_ptr + dinv (LDS hist + scan) ----------------
__global__ void k_build(const int2* __restrict__ binned, const int* __restrict__ bktBase,
                        int* __restrict__ row_ptr, float* __restrict__ dinv) {
    __shared__ int cnt[512];
    __shared__ int s1[256];
    int bk = blockIdx.x;
    int t = threadIdx.x;
    int base = bktBase[bk], end = bktBase[bk + 1];
    cnt[t] = 0; cnt[t + 256] = 0;
    __syncthreads();
    for (int i = base + t; i < end; i += 256)
        atomicAdd(&cnt[binned[i].y & 511], 1);          // LDS atomic
    __syncthreads();
    s1[t] = cnt[2 * t] + cnt[2 * t + 1];
    __syncthreads();
    int v = s1[t];
    for (int off = 1; off < 256; off <<= 1) {
        int x = (t >= off) ? s1[t - off] : 0;
        __syncthreads();
        s1[t] += x;
        __syncthreads();
    }
    int ep = s1[t] - v;                                  // exclusive over pairs
    int node = bk * 512 + 2 * t;
    row_ptr[node] = base + ep;
    row_ptr[node + 1] = base + ep + cnt[2 * t];
    dinv[node] = rsqrtf((float)cnt[2 * t] + 1.0f);       // +1 self loop
    dinv[node + 1] = rsqrtf((float)cnt[2 * t + 1] + 1.0f);
}

// ---------------- gemm body: hw(fp16) = hin(f32) @ W ----------------
// 64 nodes per tile; h staged transposed in LDS; unroll capped at 8 (VGPR spill
// at full unroll caused 1.5 GB scratch traffic in round 3).
__device__ __forceinline__ void gemm_tile(int n0, int t,
                                          const float* __restrict__ hin,
                                          const float* __restrict__ W,
                                          __half* __restrict__ hw,
                                          float* Ws, float* hsT) {
    for (int i = t; i < 1024; i += 256)
        reinterpret_cast<float4*>(Ws)[i] = reinterpret_cast<const float4*>(W)[i];
    for (int i = t; i < 1024; i += 256) {
        int node = i & 63;
        int kq = i >> 6;
        int n = n0 + node;
        float4 val = (n < NN) ? *reinterpret_cast<const float4*>(&hin[(long)n * HD + kq * 4])
                              : make_float4(0.f, 0.f, 0.f, 0.f);
        hsT[(kq * 4 + 0) * 64 + node] = val.x;
        hsT[(kq * 4 + 1) * 64 + node] = val.y;
        hsT[(kq * 4 + 2) * 64 + node] = val.z;
        hsT[(kq * 4 + 3) * 64 + node] = val.w;
    }
    __syncthreads();
    int fq = t & 15;
    int ng = t >> 4;
    float4 a0 = {0,0,0,0}, a1 = {0,0,0,0}, a2 = {0,0,0,0}, a3 = {0,0,0,0};
#pragma unroll 8
    for (int k = 0; k < HD; ++k) {
        float4 w = *reinterpret_cast<const float4*>(&Ws[k * HD + fq * 4]);
        float4 h4 = *reinterpret_cast<const float4*>(&hsT[k * 64 + ng * 4]);
        a0.x = fmaf(h4.x, w.x, a0.x); a0.y = fmaf(h4.x, w.y, a0.y);
        a0.z = fmaf(h4.x, w.z, a0.z); a0.w = fmaf(h4.x, w.w, a0.w);
        a1.x = fmaf(h4.y, w.x, a1.x); a1.y = fmaf(h4.y, w.y, a1.y);
        a1.z = fmaf(h4.y, w.z, a1.z); a1.w = fmaf(h4.y, w.w, a1.w);
        a2.x = fmaf(h4.z, w.x, a2.x); a2.y = fmaf(h4.z, w.y, a2.y);
        a2.z = fmaf(h4.z, w.z, a2.z); a2.w = fmaf(h4.z, w.w, a2.w);
        a3.x = fmaf(h4.w, w.x, a3.x); a3.y = fmaf(h4.w, w.y, a3.y);
        a3.z = fmaf(h4.w, w.z, a3.z); a3.w = fmaf(h4.w, w.w, a3.w);
    }
    int nb = n0 + ng * 4;
    float4 accs[4] = {a0, a1, a2, a3};
#pragma unroll
    for (int q = 0; q < 4; ++q) {
        if (nb + q < NN) {
            __half2 lo = __floats2half2_rn(accs[q].x, accs[q].y);
            __half2 hi = __floats2half2_rn(accs[q].z, accs[q].w);
            int2 pk;
            pk.x = *reinterpret_cast<int*>(&lo);
            pk.y = *reinterpret_cast<int*>(&hi);
            *reinterpret_cast<int2*>(&hw[(long)(nb + q) * HD + fq * 4]) = pk;
        }
    }
}

// ---------------- fused: fill entries {src, coef} (row_ptr as cursors) || gemm1 ----------------
__global__ void k_fill_gemm1(const int2* __restrict__ binned, const int* __restrict__ bktBase,
                             const int* __restrict__ row_ptr, const float* __restrict__ dinv,
                             int2* __restrict__ ent,
                             const float* __restrict__ hin, const float* __restrict__ W,
                             __half* __restrict__ hw) {
    __shared__ float Ws[HD * HD];       // gemm path
    __shared__ float hsT[HD * 64];
    __shared__ int cur[512];            // fill path
    int t = threadIdx.x;
    if (blockIdx.x < NBK) {
        int bk = blockIdx.x;
        int base = bktBase[bk], end = bktBase[bk + 1];
        cur[t] = row_ptr[bk * 512 + t];                  // global positions
        cur[t + 256] = row_ptr[bk * 512 + 256 + t];
        __syncthreads();
        for (int i = base + t; i < end; i += 256) {
            int2 ed = binned[i];
            int pos = atomicAdd(&cur[ed.y & 511], 1);    // LDS atomic
            float c = dinv[ed.x] * dinv[ed.y];           // premultiplied coef
            ent[pos] = make_int2(ed.x, __float_as_int(c));
        }
        return;
    }
    gemm_tile((blockIdx.x - NBK) * 64, t, hin, W, hw, Ws, hsT);
}

// ---------------- gather + self-loop + BN + ReLU (+ fused gemm2 OR classifier) ----------------
// one wave per node; 4 groups x 16 lanes (proven shape); lane reads int2 = 4 fp16
// features; entries carry premultiplied coef.
// MODE 0: epilogue computes hw2 = h1 @ Wn (per-node row-GEMM, all 64 lanes) -> outH fp16.
// MODE 1: epilogue computes classifier -> outF.
template <int MODE>
__global__ void k_gather_t(const __half* __restrict__ hw, const float* __restrict__ dinv,
                           const int* __restrict__ row_ptr, const int2* __restrict__ ent,
                           const float* __restrict__ bias, const float* __restrict__ g,
                           const float* __restrict__ be, const float* __restrict__ m,
                           const float* __restrict__ v,
                           const float* __restrict__ Wn, const float* __restrict__ bn,
                           __half* __restrict__ outH, float* __restrict__ outF) {
    __shared__ float h1s[4][HD];         // per-wave h1 row (MODE 0)
    int t = threadIdx.x;
    int n = blockIdx.x * 4 + (t >> 6);   // 4*GAT_NB == NN: always valid
    int l = t & 63;
    int grp = l >> 4;                    // 0..3
    int j = l & 15;                      // feature quad
    float4 acc = {0.f, 0.f, 0.f, 0.f};
    int b0 = row_ptr[n], b1 = row_ptr[n + 1];
    int e = b0 + grp;
    int2 en;
    if (e < b1) en = ent[e];
    while (e < b1) {
        int e2 = e + 4;
        int2 nx;
        if (e2 < b1) nx = ent[e2];       // prefetch next entry for this group
        float c = __int_as_float(en.y);
        int2 rv = *reinterpret_cast<const int2*>(&hw[(long)en.x * HD + j * 4]);
        float2 f0 = __half22float2(*reinterpret_cast<__half2*>(&rv.x));
        float2 f1 = __half22float2(*reinterpret_cast<__half2*>(&rv.y));
        acc.x = fmaf(f0.x, c, acc.x);
        acc.y = fmaf(f0.y, c, acc.y);
        acc.z = fmaf(f1.x, c, acc.z);
        acc.w = fmaf(f1.y, c, acc.w);
        en = nx; e = e2;
    }
    // butterfly across the 4 groups (same j) — afterwards ALL lanes hold the sum
#pragma unroll
    for (int off = 16; off < 64; off <<= 1) {
        acc.x += __shfl_xor(acc.x, off, 64);
        acc.y += __shfl_xor(acc.y, off, 64);
        acc.z += __shfl_xor(acc.z, off, 64);
        acc.w += __shfl_xor(acc.w, off, 64);
    }
    // self-loop + BN + ReLU on all lanes (values identical across groups)
    float di = dinv[n];
    float dd = di * di;
    int2 sv = *reinterpret_cast<const int2*>(&hw[(long)n * HD + j * 4]);
    float2 s0 = __half22float2(*reinterpret_cast<__half2*>(&sv.x));
    float2 s1 = __half22float2(*reinterpret_cast<__half2*>(&sv.y));
    acc.x = fmaf(s0.x, dd, acc.x);
    acc.y = fmaf(s0.y, dd, acc.y);
    acc.z = fmaf(s1.x, dd, acc.z);
    acc.w = fmaf(s1.y, dd, acc.w);
    int f = j * 4;
    float4 gv = *reinterpret_cast<const float4*>(&g[f]);
    float4 vv = *reinterpret_cast<const float4*>(&v[f]);
    float4 bv = *reinterpret_cast<const float4*>(&bias[f]);
    float4 mv = *reinterpret_cast<const float4*>(&m[f]);
    float4 bev = *reinterpret_cast<const float4*>(&be[f]);
    float o0 = fmaxf((acc.x + bv.x - mv.x) * (gv.x * rsqrtf(vv.x + BN_EPS)) + bev.x, 0.f);
    float o1 = fmaxf((acc.y + bv.y - mv.y) * (gv.y * rsqrtf(vv.y + BN_EPS)) + bev.y, 0.f);
    float o2 = fmaxf((acc.z + bv.z - mv.z) * (gv.z * rsqrtf(vv.z + BN_EPS)) + bev.z, 0.f);
    float o3 = fmaxf((acc.w + bv.w - mv.w) * (gv.w * rsqrtf(vv.w + BN_EPS)) + bev.w, 0.f);
    if (MODE == 0) {
        // fused gemm2: hw2[n][l] = sum_k h1[k] * Wn[k][l]
        int wid = t >> 6;
        if (grp == 0) *reinterpret_cast<float4*>(&h1s[wid][f]) = make_float4(o0, o1, o2, o3);
        __syncthreads();                 // all threads reach (no early exits)
        float o = 0.f;
#pragma unroll 8
        for (int k = 0; k < HD; ++k)
            o = fmaf(h1s[wid][k], Wn[k * HD + l], o);   // LDS broadcast + coalesced W2
        outH[(long)n * HD + l] = __float2half(o);
    } else if (grp == 0) {
        // classifier epilogue: lane j covers k = 4j..4j+3 of h
        float c0 = 0.f, c1 = 0.f, c2 = 0.f, c3 = 0.f, c4 = 0.f, c5 = 0.f;
#define ACCW(oq, kk) { const float* wr = &Wn[(kk) * NC]; \
        c0 = fmaf(oq, wr[0], c0); c1 = fmaf(oq, wr[1], c1); c2 = fmaf(oq, wr[2], c2); \
        c3 = fmaf(oq, wr[3], c3); c4 = fmaf(oq, wr[4], c4); c5 = fmaf(oq, wr[5], c5); }
        ACCW(o0, f + 0) ACCW(o1, f + 1) ACCW(o2, f + 2) ACCW(o3, f + 3)
#undef ACCW
#pragma unroll
        for (int off = 1; off < 16; off <<= 1) {
            c0 += __shfl_xor(c0, off, 64); c1 += __shfl_xor(c1, off, 64);
            c2 += __shfl_xor(c2, off, 64); c3 += __shfl_xor(c3, off, 64);
            c4 += __shfl_xor(c4, off, 64); c5 += __shfl_xor(c5, off, 64);
        }
        if (j == 0) {
            float* op = &outF[(long)n * NC];
            op[0] = c0 + bn[0]; op[1] = c1 + bn[1]; op[2] = c2 + bn[2];
            op[3] = c3 + bn[3]; op[4] = c4 + bn[4]; op[5] = c5 + bn[5];
        }
    }
}

extern "C" void kernel_launch(void* const* d_in, const int* in_sizes, int n_in,
                              void* d_out, int out_size, void* d_ws, size_t ws_size,
                              hipStream_t stream) {
    const float* x     = (const float*)d_in[0];
    const int*   ei    = (const int*)d_in[1];
    const float* W_emb = (const float*)d_in[2];
    const float* b_emb = (const float*)d_in[3];
    const float* W1    = (const float*)d_in[4];
    const float* b1    = (const float*)d_in[5];
    const float* g1    = (const float*)d_in[6];
    const float* be1   = (const float*)d_in[7];
    const float* m1    = (const float*)d_in[8];
    const float* v1    = (const float*)d_in[9];
    const float* W2    = (const float*)d_in[10];
    const float* b2    = (const float*)d_in[11];
    const float* g2    = (const float*)d_in[12];
    const float* be2   = (const float*)d_in[13];
    const float* m2    = (const float*)d_in[14];
    const float* v2    = (const float*)d_in[15];
    const float* W_cls = (const float*)d_in[16];
    const float* b_cls = (const float*)d_in[17];
    float* out = (float*)d_out;

    const int* src = ei;          // edge_index[0]
    const int* dst = ei + NE;     // edge_index[1]

    const long NP = 100352;                       // 196*512, >= NN+1
    float* dinv    = (float*)d_ws;                // NP
    int*   row_ptr = (int*)(dinv + NP);           // NP
    int*   bktCnt  = row_ptr + NP;                // 256
    int*   bktBase = bktCnt + 256;                // 512 (need 197)
    int*   cursor  = bktBase + 512;               // 256
    int2*  binned  = (int2*)(cursor + 256);       // NE * 8B
    int2*  ent     = binned + NE;                 // NE * 8B
    float* bufA    = (float*)(ent + NE);          // N*H f32 (embed h0)
    __half* hwH    = (__half*)(bufA + (long)NN * HD);   // N*H fp16 (layer-1 hw)
    __half* hw2H   = hwH + (long)NN * HD;               // N*H fp16 (layer-2 hw)

    // zero bucket counters (1 KB)
    hipMemsetAsync(bktCnt, 0, 256 * sizeof(int), stream);

    // coarse LDS histogram || embed
    k_hist_embed<<<MB1 + EMB_NB, 256, 0, stream>>>(dst, bktCnt, x, W_emb, b_emb, bufA);

    // bucket scan + cursor init
    k_bkt_scan<<<1, 256, 0, stream>>>(bktCnt, bktBase, cursor);

    // bin edges into bucket-contiguous regions
    k_bin<<<MB1, 256, 0, stream>>>(src, dst, cursor, binned);

    // per-bucket row_ptr + dinv
    k_build<<<NBK, 256, 0, stream>>>(binned, bktBase, row_ptr, dinv);

    // fill entries {src, coef} || gemm layer 1 (f32 -> fp16)
    k_fill_gemm1<<<NBK + GEMM_NB, 256, 0, stream>>>(binned, bktBase, row_ptr, dinv, ent,
                                                    bufA, W1, hwH);

    // gather layer 1 + BN + ReLU + fused gemm2 -> hw2H (fp16)
    k_gather_t<0><<<GAT_NB, 256, 0, stream>>>(hwH, dinv, row_ptr, ent,
                                              b1, g1, be1, m1, v1,
                                              W2, nullptr, hw2H, nullptr);

    // gather layer 2 + BN + ReLU + classifier -> out
    k_gather_t<1><<<GAT_NB, 256, 0, stream>>>(hw2H, dinv, row_ptr, ent,
                                              b2, g2, be2, m2, v2,
                                              W_cls, b_cls, nullptr, out);
}

// Round 40
// 220.307 us; speedup vs baseline: 1.1230x; 1.1230x over previous
//
#include <hip/hip_runtime.h>
#include <hip/hip_fp16.h>

#define NN 100000      // nodes
#define NE 1200000     // edges
#define FIN 22
#define HD 64
#define NC 6
#define BN_EPS 1e-5f
#define EPB 4096                          // edges per phase-1 block
#define MB1 ((NE + EPB - 1) / EPB)        // 293
#define NBK 196                           // coarse buckets of 512 nodes (dst>>9)
#define ENPB 16                           // nodes per embed block
#define EMB_NB (NN / ENPB)                // 6250 (exact)
#define GAT_NB ((NN + 3) / 4)             // 25000
#define GEMM_NB ((NN + 63) / 64)          // 1563

// ---------------- fused: coarse-bucket histogram (LDS) || embed (16 nodes/blk) ----------------
__global__ void k_hist_embed(const int* __restrict__ dst, int* __restrict__ bktCnt,
                             const float* __restrict__ x, const float* __restrict__ W,
                             const float* __restrict__ b, float* __restrict__ h) {
    __shared__ float Ws[FIN * HD];
    __shared__ float xs[ENPB][FIN];
    __shared__ int hist[256];
    int t = threadIdx.x;
    if (blockIdx.x < MB1) {
        hist[t] = 0;
        __syncthreads();
        int e0 = blockIdx.x * EPB;
        int e1 = min(e0 + EPB, NE);
        for (int e = e0 + t; e < e1; e += 256)
            atomicAdd(&hist[dst[e] >> 9], 1);          // LDS atomic
        __syncthreads();
        if (t < NBK && hist[t] > 0) atomicAdd(&bktCnt[t], hist[t]);  // <=196/block global
        return;
    }
    int bid = blockIdx.x - MB1;
    int n0 = bid * ENPB;
    for (int i = t; i < FIN * HD; i += 256) Ws[i] = W[i];
    for (int i = t; i < ENPB * FIN; i += 256)
        xs[i / FIN][i % FIN] = x[(long)(n0 + i / FIN) * FIN + i % FIN];
    __syncthreads();
    int f = t & 63;
    int lq = t >> 6;                     // wave id 0..3 -> base node
    float bf = b[f];
    float a0 = bf, a1 = bf, a2 = bf, a3 = bf;
#pragma unroll
    for (int k = 0; k < FIN; ++k) {
        float wk = Ws[k * HD + f];
        a0 = fmaf(xs[lq][k],      wk, a0);
        a1 = fmaf(xs[lq + 4][k],  wk, a1);
        a2 = fmaf(xs[lq + 8][k],  wk, a2);
        a3 = fmaf(xs[lq + 12][k], wk, a3);
    }
    h[(long)(n0 + lq) * HD + f]      = fmaxf(a0, 0.f);
    h[(long)(n0 + lq + 4) * HD + f]  = fmaxf(a1, 0.f);
    h[(long)(n0 + lq + 8) * HD + f]  = fmaxf(a2, 0.f);
    h[(long)(n0 + lq + 12) * HD + f] = fmaxf(a3, 0.f);
}

// ---------------- bucket scan (1 block): bktBase = excl scan; cursor init ----------------
__global__ void k_bkt_scan(const int* __restrict__ bktCnt, int* __restrict__ bktBase,
                           int* __restrict__ cursor) {
    __shared__ int s[256];
    int t = threadIdx.x;
    int v = (t < NBK) ? bktCnt[t] : 0;
    s[t] = v;
    __syncthreads();
    for (int off = 1; off < 256; off <<= 1) {
        int x = (t >= off) ? s[t - off] : 0;
        __syncthreads();
        s[t] += x;
        __syncthreads();
    }
    int excl = s[t] - v;
    if (t < NBK) { bktBase[t] = excl; cursor[t] = excl; }
    if (t == NBK - 1) bktBase[NBK] = excl + v;          // = NE
}

// ---------------- bin scatter: edges -> bucket-contiguous (src,dst) pairs ----------------
__global__ void k_bin(const int* __restrict__ src, const int* __restrict__ dst,
                      int* __restrict__ cursor, int2* __restrict__ binned) {
    __shared__ int hist[256];
    __shared__ int sbase[256];
    __shared__ int lcur[256];
    int t = threadIdx.x;
    hist[t] = 0;
    __syncthreads();
    int e0 = blockIdx.x * EPB;
    int e1 = min(e0 + EPB, NE);
    for (int e = e0 + t; e < e1; e += 256)
        atomicAdd(&hist[dst[e] >> 9], 1);
    __syncthreads();
    if (hist[t] > 0) sbase[t] = atomicAdd(&cursor[t], hist[t]);  // claim range
    lcur[t] = 0;
    __syncthreads();
    for (int e = e0 + t; e < e1; e += 256) {
        int d = dst[e];
        int bk = d >> 9;
        int idx = atomicAdd(&lcur[bk], 1);              // LDS atomic
        binned[sbase[bk] + idx] = make_int2(src[e], d);
    }
}

// ---------------- per-bucket row_ptr + dinv (LDS hist + scan) ----------------
__global__ void k_build(const int2* __restrict__ binned, const int* __restrict__ bktBase,
                        int* __restrict__ row_ptr, float* __restrict__ dinv) {
    __shared__ int cnt[512];
    __shared__ int s1[256];
    int bk = blockIdx.x;
    int t = threadIdx.x;
    int base = bktBase[bk], end = bktBase[bk + 1];
    cnt[t] = 0; cnt[t + 256] = 0;
    __syncthreads();
    for (int i = base + t; i < end; i += 256)
        atomicAdd(&cnt[binned[i].y & 511], 1);          // LDS atomic
    __syncthreads();
    s1[t] = cnt[2 * t] + cnt[2 * t + 1];
    __syncthreads();
    int v = s1[t];
    for (int off = 1; off < 256; off <<= 1) {
        int x = (t >= off) ? s1[t - off] : 0;
        __syncthreads();
        s1[t] += x;
        __syncthreads();
    }
    int ep = s1[t] - v;                                  // exclusive over pairs
    int node = bk * 512 + 2 * t;
    row_ptr[node] = base + ep;
    row_ptr[node + 1] = base + ep + cnt[2 * t];
    dinv[node] = rsqrtf((float)cnt[2 * t] + 1.0f);       // +1 self loop
    dinv[node + 1] = rsqrtf((float)cnt[2 * t + 1] + 1.0f);
}

// ---------------- gemm body: hw(fp16) = hin(f32) @ W ----------------
// 64 nodes per tile; h staged transposed in LDS; unroll capped at 8 (VGPR spill
// at full unroll caused 1.5 GB scratch traffic in round 3).
__device__ __forceinline__ void gemm_tile(int n0, int t,
                                          const float* __restrict__ hin,
                                          const float* __restrict__ W,
                                          __half* __restrict__ hw,
                                          float* Ws, float* hsT) {
    for (int i = t; i < 1024; i += 256)
        reinterpret_cast<float4*>(Ws)[i] = reinterpret_cast<const float4*>(W)[i];
    for (int i = t; i < 1024; i += 256) {
        int node = i & 63;
        int kq = i >> 6;
        int n = n0 + node;
        float4 val = (n < NN) ? *reinterpret_cast<const float4*>(&hin[(long)n * HD + kq * 4])
                              : make_float4(0.f, 0.f, 0.f, 0.f);
        hsT[(kq * 4 + 0) * 64 + node] = val.x;
        hsT[(kq * 4 + 1) * 64 + node] = val.y;
        hsT[(kq * 4 + 2) * 64 + node] = val.z;
        hsT[(kq * 4 + 3) * 64 + node] = val.w;
    }
    __syncthreads();
    int fq = t & 15;
    int ng = t >> 4;
    float4 a0 = {0,0,0,0}, a1 = {0,0,0,0}, a2 = {0,0,0,0}, a3 = {0,0,0,0};
#pragma unroll 8
    for (int k = 0; k < HD; ++k) {
        float4 w = *reinterpret_cast<const float4*>(&Ws[k * HD + fq * 4]);
        float4 h4 = *reinterpret_cast<const float4*>(&hsT[k * 64 + ng * 4]);
        a0.x = fmaf(h4.x, w.x, a0.x); a0.y = fmaf(h4.x, w.y, a0.y);
        a0.z = fmaf(h4.x, w.z, a0.z); a0.w = fmaf(h4.x, w.w, a0.w);
        a1.x = fmaf(h4.y, w.x, a1.x); a1.y = fmaf(h4.y, w.y, a1.y);
        a1.z = fmaf(h4.y, w.z, a1.z); a1.w = fmaf(h4.y, w.w, a1.w);
        a2.x = fmaf(h4.z, w.x, a2.x); a2.y = fmaf(h4.z, w.y, a2.y);
        a2.z = fmaf(h4.z, w.z, a2.z); a2.w = fmaf(h4.z, w.w, a2.w);
        a3.x = fmaf(h4.w, w.x, a3.x); a3.y = fmaf(h4.w, w.y, a3.y);
        a3.z = fmaf(h4.w, w.z, a3.z); a3.w = fmaf(h4.w, w.w, a3.w);
    }
    int nb = n0 + ng * 4;
    float4 accs[4] = {a0, a1, a2, a3};
#pragma unroll
    for (int q = 0; q < 4; ++q) {
        if (nb + q < NN) {
            __half2 lo = __floats2half2_rn(accs[q].x, accs[q].y);
            __half2 hi = __floats2half2_rn(accs[q].z, accs[q].w);
            int2 pk;
            pk.x = *reinterpret_cast<int*>(&lo);
            pk.y = *reinterpret_cast<int*>(&hi);
            *reinterpret_cast<int2*>(&hw[(long)(nb + q) * HD + fq * 4]) = pk;
        }
    }
}

// ---------------- fused: fill entries {src, coef} (row_ptr as cursors) || gemm1 ----------------
__global__ void k_fill_gemm1(const int2* __restrict__ binned, const int* __restrict__ bktBase,
                             const int* __restrict__ row_ptr, const float* __restrict__ dinv,
                             int2* __restrict__ ent,
                             const float* __restrict__ hin, const float* __restrict__ W,
                             __half* __restrict__ hw) {
    __shared__ float Ws[HD * HD];       // gemm path
    __shared__ float hsT[HD * 64];
    __shared__ int cur[512];            // fill path
    int t = threadIdx.x;
    if (blockIdx.x < NBK) {
        int bk = blockIdx.x;
        int base = bktBase[bk], end = bktBase[bk + 1];
        cur[t] = row_ptr[bk * 512 + t];                  // global positions
        cur[t + 256] = row_ptr[bk * 512 + 256 + t];
        __syncthreads();
        for (int i = base + t; i < end; i += 256) {
            int2 ed = binned[i];
            int pos = atomicAdd(&cur[ed.y & 511], 1);    // LDS atomic
            float c = dinv[ed.x] * dinv[ed.y];           // premultiplied coef
            ent[pos] = make_int2(ed.x, __float_as_int(c));
        }
        return;
    }
    gemm_tile((blockIdx.x - NBK) * 64, t, hin, W, hw, Ws, hsT);
}

// ---------------- layer-2 gemm ----------------
__global__ void k_gemm(const float* __restrict__ hin, const float* __restrict__ W,
                       __half* __restrict__ hw) {
    __shared__ float Ws[HD * HD];
    __shared__ float hsT[HD * 64];
    gemm_tile(blockIdx.x * 64, threadIdx.x, hin, W, hw, Ws, hsT);
}

// ---------------- gather + self-loop + BN + ReLU (+ classifier) ----------------
// one wave per node; 4 groups x 16 lanes; lane reads int2 = 4 fp16 features.
// Depth-2 pipeline: 2 clamped row-loads + 2 entry prefetches in flight per
// group (8 rows/wave) — branchless tail via zeroed coef. No block barrier.
template <int WITH_CLS>
__global__ void k_gather_bn_t(const __half* __restrict__ hw, const float* __restrict__ dinv,
                              const int* __restrict__ row_ptr, const int2* __restrict__ ent,
                              const float* __restrict__ bias, const float* __restrict__ g,
                              const float* __restrict__ be, const float* __restrict__ m,
                              const float* __restrict__ v, float* __restrict__ out,
                              const float* __restrict__ Wc, const float* __restrict__ bc) {
    int t = threadIdx.x;
    int n = blockIdx.x * 4 + (t >> 6);
    if (n >= NN) return;
    int l = t & 63;
    int grp = l >> 4;                    // 0..3
    int j = l & 15;                      // feature quad
    float4 acc = {0.f, 0.f, 0.f, 0.f};
    int b0 = row_ptr[n], b1 = row_ptr[n + 1];
    int e = b0 + grp;
    int2 en0 = ent[min(e, NE - 1)];
    int2 en1 = ent[min(e + 4, NE - 1)];
    while (e < b1) {
        int e8 = e + 8;
        int2 nx0 = ent[min(e8, NE - 1)];
        int2 nx1 = ent[min(e8 + 4, NE - 1)];
        bool h1 = (e + 4 < b1);
        float c0 = __int_as_float(en0.y);
        float c1 = h1 ? __int_as_float(en1.y) : 0.f;
        int i1 = h1 ? en1.x : en0.x;
        int2 rv0 = *reinterpret_cast<const int2*>(&hw[(long)en0.x * HD + j * 4]);
        int2 rv1 = *reinterpret_cast<const int2*>(&hw[(long)i1 * HD + j * 4]);
        float2 f00 = __half22float2(*reinterpret_cast<__half2*>(&rv0.x));
        float2 f01 = __half22float2(*reinterpret_cast<__half2*>(&rv0.y));
        float2 f10 = __half22float2(*reinterpret_cast<__half2*>(&rv1.x));
        float2 f11 = __half22float2(*reinterpret_cast<__half2*>(&rv1.y));
        acc.x = fmaf(f00.x, c0, acc.x); acc.y = fmaf(f00.y, c0, acc.y);
        acc.z = fmaf(f01.x, c0, acc.z); acc.w = fmaf(f01.y, c0, acc.w);
        acc.x = fmaf(f10.x, c1, acc.x); acc.y = fmaf(f10.y, c1, acc.y);
        acc.z = fmaf(f11.x, c1, acc.z); acc.w = fmaf(f11.y, c1, acc.w);
        en0 = nx0; en1 = nx1; e = e8;
    }
    // butterfly across the 4 groups (same j)
#pragma unroll
    for (int off = 16; off < 64; off <<= 1) {
        acc.x += __shfl_xor(acc.x, off, 64);
        acc.y += __shfl_xor(acc.y, off, 64);
        acc.z += __shfl_xor(acc.z, off, 64);
        acc.w += __shfl_xor(acc.w, off, 64);
    }
    if (grp == 0) {
        float di = dinv[n];
        float dd = di * di;
        int2 sv = *reinterpret_cast<const int2*>(&hw[(long)n * HD + j * 4]);
        float2 s0 = __half22float2(*reinterpret_cast<__half2*>(&sv.x));
        float2 s1 = __half22float2(*reinterpret_cast<__half2*>(&sv.y));
        acc.x = fmaf(s0.x, dd, acc.x);
        acc.y = fmaf(s0.y, dd, acc.y);
        acc.z = fmaf(s1.x, dd, acc.z);
        acc.w = fmaf(s1.y, dd, acc.w);
        int f = j * 4;
        float4 gv = *reinterpret_cast<const float4*>(&g[f]);
        float4 vv = *reinterpret_cast<const float4*>(&v[f]);
        float4 bv = *reinterpret_cast<const float4*>(&bias[f]);
        float4 mv = *reinterpret_cast<const float4*>(&m[f]);
        float4 bev = *reinterpret_cast<const float4*>(&be[f]);
        float o0 = fmaxf((acc.x + bv.x - mv.x) * (gv.x * rsqrtf(vv.x + BN_EPS)) + bev.x, 0.f);
        float o1 = fmaxf((acc.y + bv.y - mv.y) * (gv.y * rsqrtf(vv.y + BN_EPS)) + bev.y, 0.f);
        float o2 = fmaxf((acc.z + bv.z - mv.z) * (gv.z * rsqrtf(vv.z + BN_EPS)) + bev.z, 0.f);
        float o3 = fmaxf((acc.w + bv.w - mv.w) * (gv.w * rsqrtf(vv.w + BN_EPS)) + bev.w, 0.f);
        if (WITH_CLS == 0) {
            float4 o = {o0, o1, o2, o3};
            *reinterpret_cast<float4*>(&out[(long)n * HD + f]) = o;
        } else {
            // classifier epilogue: lane j covers k = 4j..4j+3 of h
            float c0 = 0.f, c1 = 0.f, c2 = 0.f, c3 = 0.f, c4 = 0.f, c5 = 0.f;
#define ACCW(oq, kk) { const float* wr = &Wc[(kk) * NC]; \
            c0 = fmaf(oq, wr[0], c0); c1 = fmaf(oq, wr[1], c1); c2 = fmaf(oq, wr[2], c2); \
            c3 = fmaf(oq, wr[3], c3); c4 = fmaf(oq, wr[4], c4); c5 = fmaf(oq, wr[5], c5); }
            ACCW(o0, f + 0) ACCW(o1, f + 1) ACCW(o2, f + 2) ACCW(o3, f + 3)
#undef ACCW
#pragma unroll
            for (int off = 1; off < 16; off <<= 1) {
                c0 += __shfl_xor(c0, off, 64); c1 += __shfl_xor(c1, off, 64);
                c2 += __shfl_xor(c2, off, 64); c3 += __shfl_xor(c3, off, 64);
                c4 += __shfl_xor(c4, off, 64); c5 += __shfl_xor(c5, off, 64);
            }
            if (j == 0) {
                float* op = &out[(long)n * NC];
                op[0] = c0 + bc[0]; op[1] = c1 + bc[1]; op[2] = c2 + bc[2];
                op[3] = c3 + bc[3]; op[4] = c4 + bc[4]; op[5] = c5 + bc[5];
            }
        }
    }
}

extern "C" void kernel_launch(void* const* d_in, const int* in_sizes, int n_in,
                              void* d_out, int out_size, void* d_ws, size_t ws_size,
                              hipStream_t stream) {
    const float* x     = (const float*)d_in[0];
    const int*   ei    = (const int*)d_in[1];
    const float* W_emb = (const float*)d_in[2];
    const float* b_emb = (const float*)d_in[3];
    const float* W1    = (const float*)d_in[4];
    const float* b1    = (const float*)d_in[5];
    const float* g1    = (const float*)d_in[6];
    const float* be1   = (const float*)d_in[7];
    const float* m1    = (const float*)d_in[8];
    const float* v1    = (const float*)d_in[9];
    const float* W2    = (const float*)d_in[10];
    const float* b2    = (const float*)d_in[11];
    const float* g2    = (const float*)d_in[12];
    const float* be2   = (const float*)d_in[13];
    const float* m2    = (const float*)d_in[14];
    const float* v2    = (const float*)d_in[15];
    const float* W_cls = (const float*)d_in[16];
    const float* b_cls = (const float*)d_in[17];
    float* out = (float*)d_out;

    const int* src = ei;          // edge_index[0]
    const int* dst = ei + NE;     // edge_index[1]

    const long NP = 100352;                       // 196*512, >= NN+1
    float* dinv    = (float*)d_ws;                // NP
    int*   row_ptr = (int*)(dinv + NP);           // NP
    int*   bktCnt  = row_ptr + NP;                // 256
    int*   bktBase = bktCnt + 256;                // 512 (need 197)
    int*   cursor  = bktBase + 512;               // 256
    int2*  binned  = (int2*)(cursor + 256);       // NE * 8B
    int2*  ent     = binned + NE;                 // NE * 8B
    float* bufA    = (float*)(ent + NE);          // N*H f32
    __half* hwH    = (__half*)(bufA + (long)NN * HD);  // N*H fp16

    // zero bucket counters (1 KB)
    hipMemsetAsync(bktCnt, 0, 256 * sizeof(int), stream);

    // coarse LDS histogram || embed
    k_hist_embed<<<MB1 + EMB_NB, 256, 0, stream>>>(dst, bktCnt, x, W_emb, b_emb, bufA);

    // bucket scan + cursor init
    k_bkt_scan<<<1, 256, 0, stream>>>(bktCnt, bktBase, cursor);

    // bin edges into bucket-contiguous regions
    k_bin<<<MB1, 256, 0, stream>>>(src, dst, cursor, binned);

    // per-bucket row_ptr + dinv
    k_build<<<NBK, 256, 0, stream>>>(binned, bktBase, row_ptr, dinv);

    // fill entries {src, coef} || gemm layer 1 (f32 -> fp16)
    k_fill_gemm1<<<NBK + GEMM_NB, 256, 0, stream>>>(binned, bktBase, row_ptr, dinv, ent,
                                                    bufA, W1, hwH);

    // gather layer 1 -> bufA (f32)
    k_gather_bn_t<0><<<GAT_NB, 256, 0, stream>>>(hwH, dinv, row_ptr, ent,
                                                 b1, g1, be1, m1, v1, bufA,
                                                 nullptr, nullptr);
    // gemm layer 2 (f32 -> fp16)
    k_gemm<<<GEMM_NB, 256, 0, stream>>>(bufA, W2, hwH);

    // gather layer 2 + BN + ReLU + classifier -> out
    k_gather_bn_t<1><<<GAT_NB, 256, 0, stream>>>(hwH, dinv, row_ptr, ent,
                                                 b2, g2, be2, m2, v2, out,
                                                 W_cls, b_cls);
}